// Round 3
// baseline (273.908 us; speedup 1.0000x reference)
//
#include <hip/hip_runtime.h>

// Masked dot-product attention. INPUTS float32, OUTPUT float32.
// B=32, Q=K=2048, D=128. Flash-style online softmax,
// swapped-QK^T 32x32x16 bf16 MFMA structure (learn_hip m214 lineage).

using bf16   = __bf16;
using bf16x2 = __attribute__((ext_vector_type(2)))  __bf16;
using bf16x4 = __attribute__((ext_vector_type(4)))  __bf16;
using bf16x8 = __attribute__((ext_vector_type(8)))  __bf16;
using f32x4  = __attribute__((ext_vector_type(4)))  float;
using f32x16 = __attribute__((ext_vector_type(16))) float;

constexpr int BATCH = 32;
constexpr int QLEN  = 2048;
constexpr int KLEN  = 2048;
constexpr int DH    = 128;
constexpr int QBLK  = 128;   // q-rows per block (4 waves x 32)
constexpr int KVBLK = 64;    // kv tile

// K tile: [64 keys][128 d] bf16, row stride 256B, XOR swizzle by key (G4 fix
// for the 32-way conflict of D=128 row-major ds_read_b128).
__device__ __forceinline__ int swzK(int key, int byteoff) {
  return (key * 256 + byteoff) ^ ((key & 7) << 4);
}
// V^T tile: [128 d][64 keys] bf16, row stride 128B. Swizzle mixes d&7 and
// (d>>3)&7 so BOTH the staging writes (d0 multiple of 8 -> d&7 uniform) and
// the frag reads (d = 32*db + lane) spread across banks.
__device__ __forceinline__ int swzV(int d, int byteoff) {
  return (d * 128 + byteoff) ^ (((d ^ (d >> 3)) & 7) << 4);
}

__global__ __launch_bounds__(256)
void fa_fwd(const float* __restrict__ Qg, const float* __restrict__ Kg,
            const float* __restrict__ Vg, const int* __restrict__ Lg,
            float* __restrict__ Og)
{
  __shared__ bf16 s_k [KVBLK * DH];    // 16 KB, swizzled
  __shared__ bf16 s_vt[DH * KVBLK];    // 16 KB, swizzled, d-major
  __shared__ bf16 s_p [4][32 * 72];    // 18 KB, per-wave P, row stride 144B

  const int tid  = threadIdx.x;
  const int wave = tid >> 6;
  const int lane = tid & 63;
  const int c    = lane & 31;   // q-row within wave (S^T col) / d-col (PV)
  const int hi   = lane >> 5;

  const int bid   = blockIdx.x;
  const int batch = bid & (BATCH - 1);   // batch-interleaved for load balance
  const int qtile = bid >> 5;
  const int L  = Lg[batch];
  const int nt = (L + KVBLK - 1) / KVBLK;

  const size_t baseQ  = ((size_t)batch * QLEN + (size_t)qtile * QBLK) * DH;
  const size_t baseKV = (size_t)batch * KLEN * DH;

  // Q fragments for this wave's 32 rows; thread's row = c.
  // B-frag layout for 32x32x16: col = lane&31 (q-row), k = 8*hi + i (d).
  bf16x8 qf[8];
  {
    const float* qp = Qg + baseQ + (size_t)(wave * 32 + c) * DH + hi * 8;
    #pragma unroll
    for (int dc = 0; dc < 8; ++dc) {
      f32x4 a = *(const f32x4*)(qp + dc * 16);
      f32x4 b = *(const f32x4*)(qp + dc * 16 + 4);
      #pragma unroll
      for (int j = 0; j < 4; ++j) {
        qf[dc][j]     = (bf16)a[j];
        qf[dc][4 + j] = (bf16)b[j];
      }
    }
  }

  f32x16 o[4];
  #pragma unroll
  for (int db = 0; db < 4; ++db)
    #pragma unroll
    for (int j = 0; j < 16; ++j) o[db][j] = 0.f;
  float m = -__builtin_inff();
  float l = 0.f;

  bf16* pw = &s_p[wave][0];
  const float SC = 0.08838834764831845f * 1.4426950408889634f; // log2e/sqrt(D)

  for (int kt = 0; kt < nt; ++kt) {
    const int k0 = kt * KVBLK;
    __syncthreads();   // previous-tile reads done before restaging

    // ---- stage K (f32 -> bf16; zero-fill past L so MFMA output finite) ----
    #pragma unroll
    for (int s = 0; s < 4; ++s) {
      int id  = tid + 256 * s;
      int key = id >> 4;     // 0..63
      int i8  = id & 15;     // d chunk of 8
      bf16x8 val = {};
      if (k0 + key < L) {
        const float* src = Kg + baseKV + (size_t)(k0 + key) * DH + i8 * 8;
        f32x4 a = *(const f32x4*)(src);
        f32x4 b = *(const f32x4*)(src + 4);
        #pragma unroll
        for (int j = 0; j < 4; ++j) { val[j] = (bf16)a[j]; val[4 + j] = (bf16)b[j]; }
      }
      *(bf16x8*)((char*)s_k + swzK(key, i8 * 16)) = val;
    }
    // ---- stage V^T (f32 -> bf16; pairs of keys packed per b32 write) ----
    #pragma unroll
    for (int s = 0; s < 2; ++s) {
      int id = tid + 256 * s;
      int p2 = id >> 4;      // key pair 0..31
      int i8 = id & 15;
      f32x4 v0a = {}, v0b = {}, v1a = {}, v1b = {};
      if (k0 + 2 * p2 < L) {
        const float* src = Vg + baseKV + (size_t)(k0 + 2 * p2) * DH + i8 * 8;
        v0a = *(const f32x4*)(src);
        v0b = *(const f32x4*)(src + 4);
      }
      if (k0 + 2 * p2 + 1 < L) {
        const float* src = Vg + baseKV + (size_t)(k0 + 2 * p2 + 1) * DH + i8 * 8;
        v1a = *(const f32x4*)(src);
        v1b = *(const f32x4*)(src + 4);
      }
      #pragma unroll
      for (int j = 0; j < 8; ++j) {
        int d = i8 * 8 + j;
        float f0 = (j < 4) ? v0a[j & 3] : v0b[j & 3];
        float f1 = (j < 4) ? v1a[j & 3] : v1b[j & 3];
        bf16x2 pk = { (bf16)f0, (bf16)f1 };
        *(bf16x2*)((char*)s_vt + swzV(d, p2 * 4)) = pk;
      }
    }
    __syncthreads();

    // ---- S^T = K · Q^T  (lane holds q-row c; keys via regs/hi) ----
    f32x16 st[2];
    #pragma unroll
    for (int a = 0; a < 2; ++a) {
      #pragma unroll
      for (int j = 0; j < 16; ++j) st[a][j] = 0.f;
      int key = a * 32 + c;   // A-frag row = lane&31
      #pragma unroll
      for (int dc = 0; dc < 8; ++dc) {
        bf16x8 kf = *(const bf16x8*)((const char*)s_k + swzK(key, dc * 32 + hi * 16));
        st[a] = __builtin_amdgcn_mfma_f32_32x32x16_bf16(kf, qf[dc], st[a], 0, 0, 0);
      }
    }

    // ---- online softmax; key(a,r,hi) = 32a + (r&3) + 8*(r>>2) + 4*hi ----
    const bool partial = (k0 + KVBLK > L);
    float pm = -__builtin_inff();
    #pragma unroll
    for (int a = 0; a < 2; ++a)
      #pragma unroll
      for (int r = 0; r < 16; ++r) {
        float s = st[a][r] * SC;
        if (partial) {
          int key = k0 + a * 32 + (r & 3) + 8 * (r >> 2) + 4 * hi;
          if (key >= L) s = -__builtin_inff();
        }
        st[a][r] = s;
        pm = fmaxf(pm, s);
      }
    pm = fmaxf(pm, __shfl_xor(pm, 32));
    const float mnew = fmaxf(m, pm);
    const float fsc  = __builtin_amdgcn_exp2f(m - mnew);  // m=-inf -> 0
    m = mnew;

    float rs = 0.f;
    #pragma unroll
    for (int a = 0; a < 2; ++a)
      #pragma unroll
      for (int rr = 0; rr < 4; ++rr) {
        bf16x4 pk;   // 4 consecutive keys: 32a + 8rr + 4hi + j
        #pragma unroll
        for (int j = 0; j < 4; ++j) {
          float p = __builtin_amdgcn_exp2f(st[a][rr * 4 + j] - mnew);
          rs += p;
          pk[j] = (bf16)p;
        }
        *(bf16x4*)(pw + c * 72 + a * 32 + rr * 8 + hi * 4) = pk;
      }
    rs += __shfl_xor(rs, 32);
    l = l * fsc + rs;

    // ---- rescale O (O rows = (j&3)+8*(j>>2)+4hi; state lives at lane=row) ----
    float fr[16];
    #pragma unroll
    for (int j = 0; j < 16; ++j)
      fr[j] = __shfl(fsc, (j & 3) + 8 * (j >> 2) + 4 * hi, 64);
    #pragma unroll
    for (int db = 0; db < 4; ++db)
      #pragma unroll
      for (int j = 0; j < 16; ++j)
        o[db][j] *= fr[j];

    // ---- O += P · V ----
    #pragma unroll
    for (int kc = 0; kc < 4; ++kc) {
      // A-frag: row = c (q-row), k = 16kc + 8hi + i (key)
      bf16x8 pa = *(const bf16x8*)(pw + c * 72 + kc * 16 + hi * 8);
      #pragma unroll
      for (int db = 0; db < 4; ++db) {
        int d = db * 32 + c;   // B-frag: col = lane&31 (d), k = key
        bf16x8 vb = *(const bf16x8*)((const char*)s_vt + swzV(d, kc * 32 + hi * 16));
        o[db] = __builtin_amdgcn_mfma_f32_32x32x16_bf16(pa, vb, o[db], 0, 0, 0);
      }
    }
  }

  // ---- epilogue: normalize and store (f32 out) ----
  float inv[16];
  #pragma unroll
  for (int j = 0; j < 16; ++j)
    inv[j] = 1.f / __shfl(l, (j & 3) + 8 * (j >> 2) + 4 * hi, 64);

  float* op = Og + baseQ + (size_t)(wave * 32) * DH;
  #pragma unroll
  for (int db = 0; db < 4; ++db)
    #pragma unroll
    for (int j = 0; j < 16; ++j) {
      int row = (j & 3) + 8 * (j >> 2) + 4 * hi;
      op[(size_t)row * DH + db * 32 + c] = o[db][j] * inv[j];
    }
}

extern "C" void kernel_launch(void* const* d_in, const int* in_sizes, int n_in,
                              void* d_out, int out_size, void* d_ws, size_t ws_size,
                              hipStream_t stream) {
  const float* q = (const float*)d_in[0];
  const float* k = (const float*)d_in[1];
  const float* v = (const float*)d_in[2];
  const int* lens = (const int*)d_in[3];
  float* out = (float*)d_out;

  dim3 grid(BATCH * (QLEN / QBLK));   // 512 blocks, batch-interleaved
  dim3 block(256);
  hipLaunchKernelGGL(fa_fwd, grid, block, 0, stream, q, k, v, lens, out);
}

// Round 4
// 173.264 us; speedup vs baseline: 1.5809x; 1.5809x over previous
//
#include <hip/hip_runtime.h>

// Masked dot-product attention. INPUTS float32, OUTPUT float32.
// B=32, Q=K=2048, D=128. Flash-style online softmax,
// swapped-QK^T 32x32x16 bf16 MFMA structure.
// R4: pre-pass K/V -> bf16 (zero-padded) in d_ws + T14 async register
// prefetch of next KV tile + T5 setprio around MFMA clusters.

using bf16   = __bf16;
using bf16x2 = __attribute__((ext_vector_type(2)))  __bf16;
using bf16x4 = __attribute__((ext_vector_type(4)))  __bf16;
using bf16x8 = __attribute__((ext_vector_type(8)))  __bf16;
using f32x4  = __attribute__((ext_vector_type(4)))  float;
using f32x16 = __attribute__((ext_vector_type(16))) float;

constexpr int BATCH = 32;
constexpr int QLEN  = 2048;
constexpr int KLEN  = 2048;
constexpr int DH    = 128;
constexpr int QBLK  = 128;   // q-rows per block (4 waves x 32)
constexpr int KVBLK = 64;    // kv tile

// K tile: [64 keys][128 d] bf16, row stride 256B, XOR swizzle by key (G4 fix
// for the 32-way conflict of D=128 row-major ds_read_b128).
__device__ __forceinline__ int swzK(int key, int byteoff) {
  return (key * 256 + byteoff) ^ ((key & 7) << 4);
}
// V^T tile: [128 d][64 keys] bf16, row stride 128B. Swizzle mixes d&7 and
// (d>>3)&7 so BOTH the staging writes (d0 multiple of 8 -> d&7 uniform) and
// the frag reads (d = 32*db + lane) spread across banks.
__device__ __forceinline__ int swzV(int d, int byteoff) {
  return (d * 128 + byteoff) ^ (((d ^ (d >> 3)) & 7) << 4);
}

// ---- pre-pass: K,V f32 -> bf16, zero past valid_len ----
__global__ __launch_bounds__(256)
void conv_kv(const float* __restrict__ Kg, const float* __restrict__ Vg,
             const int* __restrict__ Lg, bf16* __restrict__ Kb,
             bf16* __restrict__ Vb)
{
  const int total = 2 * BATCH * KLEN * (DH / 8);   // 2^21 chunks of 8
  for (int i = blockIdx.x * blockDim.x + threadIdx.x; i < total;
       i += gridDim.x * blockDim.x) {
    const int d8    = i & 15;
    const int k     = (i >> 4) & (KLEN - 1);
    const int b     = (i >> 15) & (BATCH - 1);
    const int which = i >> 20;
    const size_t off = ((size_t)b * KLEN + k) * DH + d8 * 8;
    bf16x8 val = {};
    if (k < Lg[b]) {
      const float* src = (which ? Vg : Kg) + off;
      f32x4 a = *(const f32x4*)src;
      f32x4 c = *(const f32x4*)(src + 4);
      #pragma unroll
      for (int j = 0; j < 4; ++j) { val[j] = (bf16)a[j]; val[4 + j] = (bf16)c[j]; }
    }
    *(bf16x8*)((which ? Vb : Kb) + off) = val;
  }
}

template<bool PRE>
__global__ __launch_bounds__(256)
void fa_fwd(const float* __restrict__ Qg, const float* __restrict__ Kg,
            const float* __restrict__ Vg, const int* __restrict__ Lg,
            float* __restrict__ Og,
            const bf16* __restrict__ Kb, const bf16* __restrict__ Vb)
{
  __shared__ bf16 s_k [KVBLK * DH];    // 16 KB, swizzled
  __shared__ bf16 s_vt[DH * KVBLK];    // 16 KB, swizzled, d-major
  __shared__ bf16 s_p [4][32 * 72];    // 18 KB, per-wave P, row stride 144B

  const int tid  = threadIdx.x;
  const int wave = tid >> 6;
  const int lane = tid & 63;
  const int c    = lane & 31;   // q-row within wave (S^T col) / d-col (PV)
  const int hi   = lane >> 5;

  const int bid   = blockIdx.x;
  const int batch = bid & (BATCH - 1);   // batch-interleaved; same-batch on same XCD
  const int qtile = bid >> 5;
  const int L  = Lg[batch];
  const int nt = (L + KVBLK - 1) / KVBLK;

  const size_t baseQ  = ((size_t)batch * QLEN + (size_t)qtile * QBLK) * DH;
  const size_t baseKV = (size_t)batch * KLEN * DH;

  // Q fragments: B-frag for 32x32x16: col = lane&31 (q-row), k = 8*hi + i (d).
  bf16x8 qf[8];
  {
    const float* qp = Qg + baseQ + (size_t)(wave * 32 + c) * DH + hi * 8;
    #pragma unroll
    for (int dc = 0; dc < 8; ++dc) {
      f32x4 a = *(const f32x4*)(qp + dc * 16);
      f32x4 b = *(const f32x4*)(qp + dc * 16 + 4);
      #pragma unroll
      for (int j = 0; j < 4; ++j) {
        qf[dc][j]     = (bf16)a[j];
        qf[dc][4 + j] = (bf16)b[j];
      }
    }
  }

  f32x16 o[4];
  #pragma unroll
  for (int db = 0; db < 4; ++db)
    #pragma unroll
    for (int j = 0; j < 16; ++j) o[db][j] = 0.f;
  float m = -__builtin_inff();
  float l = 0.f;

  bf16* pw = &s_p[wave][0];
  const float SC = 0.08838834764831845f * 1.4426950408889634f; // log2e/sqrt(D)

  // T14 prefetch registers (PRE path): 8 x 16B = 32 VGPR
  bf16x8 rK[4], rV[4];
  if constexpr (PRE) {
    #pragma unroll
    for (int s = 0; s < 4; ++s) {
      int id = tid + 256 * s; int key = id >> 4; int i8 = id & 15;
      rK[s] = *(const bf16x8*)(Kb + baseKV + (size_t)key * DH + i8 * 8);
    }
    #pragma unroll
    for (int s = 0; s < 2; ++s) {
      int id = tid + 256 * s; int p2 = id >> 4; int i8 = id & 15;
      rV[2 * s]     = *(const bf16x8*)(Vb + baseKV + (size_t)(2 * p2) * DH + i8 * 8);
      rV[2 * s + 1] = *(const bf16x8*)(Vb + baseKV + (size_t)(2 * p2 + 1) * DH + i8 * 8);
    }
  }

  for (int kt = 0; kt < nt; ++kt) {
    const int k0 = kt * KVBLK;
    __syncthreads();   // previous-tile reads done before restaging

    if constexpr (PRE) {
      // ---- write prefetched regs -> LDS ----
      #pragma unroll
      for (int s = 0; s < 4; ++s) {
        int id = tid + 256 * s; int key = id >> 4; int i8 = id & 15;
        *(bf16x8*)((char*)s_k + swzK(key, i8 * 16)) = rK[s];
      }
      #pragma unroll
      for (int s = 0; s < 2; ++s) {
        int id = tid + 256 * s; int p2 = id >> 4; int i8 = id & 15;
        #pragma unroll
        for (int j = 0; j < 8; ++j) {
          bf16x2 pk = { rV[2 * s][j], rV[2 * s + 1][j] };
          *(bf16x2*)((char*)s_vt + swzV(i8 * 8 + j, p2 * 4)) = pk;
        }
      }
    } else {
      // ---- synchronous f32 staging (fallback when ws too small) ----
      #pragma unroll
      for (int s = 0; s < 4; ++s) {
        int id  = tid + 256 * s;
        int key = id >> 4;
        int i8  = id & 15;
        bf16x8 val = {};
        if (k0 + key < L) {
          const float* src = Kg + baseKV + (size_t)(k0 + key) * DH + i8 * 8;
          f32x4 a = *(const f32x4*)(src);
          f32x4 b = *(const f32x4*)(src + 4);
          #pragma unroll
          for (int j = 0; j < 4; ++j) { val[j] = (bf16)a[j]; val[4 + j] = (bf16)b[j]; }
        }
        *(bf16x8*)((char*)s_k + swzK(key, i8 * 16)) = val;
      }
      #pragma unroll
      for (int s = 0; s < 2; ++s) {
        int id = tid + 256 * s;
        int p2 = id >> 4;
        int i8 = id & 15;
        f32x4 v0a = {}, v0b = {}, v1a = {}, v1b = {};
        if (k0 + 2 * p2 < L) {
          const float* src = Vg + baseKV + (size_t)(k0 + 2 * p2) * DH + i8 * 8;
          v0a = *(const f32x4*)(src);
          v0b = *(const f32x4*)(src + 4);
        }
        if (k0 + 2 * p2 + 1 < L) {
          const float* src = Vg + baseKV + (size_t)(k0 + 2 * p2 + 1) * DH + i8 * 8;
          v1a = *(const f32x4*)(src);
          v1b = *(const f32x4*)(src + 4);
        }
        #pragma unroll
        for (int j = 0; j < 8; ++j) {
          int d = i8 * 8 + j;
          float f0 = (j < 4) ? v0a[j & 3] : v0b[j & 3];
          float f1 = (j < 4) ? v1a[j & 3] : v1b[j & 3];
          bf16x2 pk = { (bf16)f0, (bf16)f1 };
          *(bf16x2*)((char*)s_vt + swzV(d, p2 * 4)) = pk;
        }
      }
    }
    __syncthreads();

    // ---- T14: issue next tile's loads now; latency hides under compute ----
    if constexpr (PRE) {
      if (kt + 1 < nt) {
        const int kn = k0 + KVBLK;
        #pragma unroll
        for (int s = 0; s < 4; ++s) {
          int id = tid + 256 * s; int key = id >> 4; int i8 = id & 15;
          rK[s] = *(const bf16x8*)(Kb + baseKV + (size_t)(kn + key) * DH + i8 * 8);
        }
        #pragma unroll
        for (int s = 0; s < 2; ++s) {
          int id = tid + 256 * s; int p2 = id >> 4; int i8 = id & 15;
          rV[2 * s]     = *(const bf16x8*)(Vb + baseKV + (size_t)(kn + 2 * p2) * DH + i8 * 8);
          rV[2 * s + 1] = *(const bf16x8*)(Vb + baseKV + (size_t)(kn + 2 * p2 + 1) * DH + i8 * 8);
        }
      }
    }

    // ---- S^T = K · Q^T  (lane holds q-row c; keys via regs/hi) ----
    f32x16 st[2];
    __builtin_amdgcn_s_setprio(1);
    #pragma unroll
    for (int a = 0; a < 2; ++a) {
      #pragma unroll
      for (int j = 0; j < 16; ++j) st[a][j] = 0.f;
      int key = a * 32 + c;   // A-frag row = lane&31
      #pragma unroll
      for (int dc = 0; dc < 8; ++dc) {
        bf16x8 kf = *(const bf16x8*)((const char*)s_k + swzK(key, dc * 32 + hi * 16));
        st[a] = __builtin_amdgcn_mfma_f32_32x32x16_bf16(kf, qf[dc], st[a], 0, 0, 0);
      }
    }
    __builtin_amdgcn_s_setprio(0);

    // ---- online softmax; key(a,r,hi) = 32a + (r&3) + 8*(r>>2) + 4*hi ----
    const bool partial = (k0 + KVBLK > L);
    float pm = -__builtin_inff();
    #pragma unroll
    for (int a = 0; a < 2; ++a)
      #pragma unroll
      for (int r = 0; r < 16; ++r) {
        float s = st[a][r] * SC;
        if (partial) {
          int key = k0 + a * 32 + (r & 3) + 8 * (r >> 2) + 4 * hi;
          if (key >= L) s = -__builtin_inff();
        }
        st[a][r] = s;
        pm = fmaxf(pm, s);
      }
    pm = fmaxf(pm, __shfl_xor(pm, 32));
    const float mnew = fmaxf(m, pm);
    const float fsc  = __builtin_amdgcn_exp2f(m - mnew);  // m=-inf -> 0
    m = mnew;

    float rs = 0.f;
    #pragma unroll
    for (int a = 0; a < 2; ++a)
      #pragma unroll
      for (int rr = 0; rr < 4; ++rr) {
        bf16x4 pk;   // 4 consecutive keys: 32a + 8rr + 4hi + j
        #pragma unroll
        for (int j = 0; j < 4; ++j) {
          float p = __builtin_amdgcn_exp2f(st[a][rr * 4 + j] - mnew);
          rs += p;
          pk[j] = (bf16)p;
        }
        *(bf16x4*)(pw + c * 72 + a * 32 + rr * 8 + hi * 4) = pk;
      }
    rs += __shfl_xor(rs, 32);
    l = l * fsc + rs;

    // ---- rescale O (O rows = (j&3)+8*(j>>2)+4hi; state lives at lane=row) ----
    float fr[16];
    #pragma unroll
    for (int j = 0; j < 16; ++j)
      fr[j] = __shfl(fsc, (j & 3) + 8 * (j >> 2) + 4 * hi, 64);
    #pragma unroll
    for (int db = 0; db < 4; ++db)
      #pragma unroll
      for (int j = 0; j < 16; ++j)
        o[db][j] *= fr[j];

    // ---- O += P · V ----
    __builtin_amdgcn_s_setprio(1);
    #pragma unroll
    for (int kc = 0; kc < 4; ++kc) {
      // A-frag: row = c (q-row), k = 16kc + 8hi + i (key)
      bf16x8 pa = *(const bf16x8*)(pw + c * 72 + kc * 16 + hi * 8);
      #pragma unroll
      for (int db = 0; db < 4; ++db) {
        int d = db * 32 + c;   // B-frag: col = lane&31 (d), k = key
        bf16x8 vb = *(const bf16x8*)((const char*)s_vt + swzV(d, kc * 32 + hi * 16));
        o[db] = __builtin_amdgcn_mfma_f32_32x32x16_bf16(pa, vb, o[db], 0, 0, 0);
      }
    }
    __builtin_amdgcn_s_setprio(0);
  }

  // ---- epilogue: normalize and store (f32 out) ----
  float inv[16];
  #pragma unroll
  for (int j = 0; j < 16; ++j)
    inv[j] = 1.f / __shfl(l, (j & 3) + 8 * (j >> 2) + 4 * hi, 64);

  float* op = Og + baseQ + (size_t)(wave * 32) * DH;
  #pragma unroll
  for (int db = 0; db < 4; ++db)
    #pragma unroll
    for (int j = 0; j < 16; ++j) {
      int row = (j & 3) + 8 * (j >> 2) + 4 * hi;
      op[(size_t)row * DH + db * 32 + c] = o[db][j] * inv[j];
    }
}

extern "C" void kernel_launch(void* const* d_in, const int* in_sizes, int n_in,
                              void* d_out, int out_size, void* d_ws, size_t ws_size,
                              hipStream_t stream) {
  const float* q = (const float*)d_in[0];
  const float* k = (const float*)d_in[1];
  const float* v = (const float*)d_in[2];
  const int* lens = (const int*)d_in[3];
  float* out = (float*)d_out;

  dim3 grid(BATCH * (QLEN / QBLK));   // 512 blocks, batch-interleaved
  dim3 block(256);

  const size_t elems = (size_t)BATCH * KLEN * DH;
  const size_t need  = 2 * elems * sizeof(bf16);   // 33.55 MB
  if (ws_size >= need) {
    bf16* Kb = (bf16*)d_ws;
    bf16* Vb = Kb + elems;
    hipLaunchKernelGGL(conv_kv, dim3(2048), dim3(256), 0, stream, k, v, lens, Kb, Vb);
    hipLaunchKernelGGL((fa_fwd<true>), grid, block, 0, stream, q, k, v, lens, out, Kb, Vb);
  } else {
    hipLaunchKernelGGL((fa_fwd<false>), grid, block, 0, stream, q, k, v, lens, out,
                       (const bf16*)nullptr, (const bf16*)nullptr);
  }
}

// Round 5
// 121.421 us; speedup vs baseline: 2.2559x; 1.4270x over previous
//
#include <hip/hip_runtime.h>

// Masked dot-product attention. INPUTS float32, OUTPUT float32.
// B=32, Q=K=2048, D=128. Flash-style online softmax,
// swapped-QK^T 32x32x16 bf16 MFMA structure.
// R5: dynamic LPT work queue (sorted by L desc, atomic grab) to fix the
// same-batch CU-pairing imbalance + T12 in-register P exchange (s_p
// eliminated -> bank conflicts + LDS round-trip gone). Keeps R4's
// bf16 pre-pass, T14 register prefetch, T5 setprio.

using bf16   = __bf16;
using bf16x2 = __attribute__((ext_vector_type(2)))  __bf16;
using bf16x4 = __attribute__((ext_vector_type(4)))  __bf16;
using bf16x8 = __attribute__((ext_vector_type(8)))  __bf16;
using f32x4  = __attribute__((ext_vector_type(4)))  float;
using f32x16 = __attribute__((ext_vector_type(16))) float;

constexpr int BATCH  = 32;
constexpr int QLEN   = 2048;
constexpr int KLEN   = 2048;
constexpr int DH     = 128;
constexpr int QBLK   = 128;   // q-rows per item (4 waves x 32)
constexpr int KVBLK  = 64;    // kv tile
constexpr int NITEMS = BATCH * (QLEN / QBLK);   // 512

union U4 { bf16x4 h; uint2 u; };

// K tile: [64 keys][128 d] bf16, row stride 256B, XOR swizzle by key.
__device__ __forceinline__ int swzK(int key, int byteoff) {
  return (key * 256 + byteoff) ^ ((key & 7) << 4);
}
// V^T tile: [128 d][64 keys] bf16, row stride 128B.
__device__ __forceinline__ int swzV(int d, int byteoff) {
  return (d * 128 + byteoff) ^ (((d ^ (d >> 3)) & 7) << 4);
}

// ---- pre-pass: K,V f32 -> bf16 (zero past valid_len) + LPT plan ----
__global__ __launch_bounds__(256)
void conv_kv(const float* __restrict__ Kg, const float* __restrict__ Vg,
             const int* __restrict__ Lg, bf16* __restrict__ Kb,
             bf16* __restrict__ Vb, int* __restrict__ order,
             int* __restrict__ counter)
{
  if (blockIdx.x == 0 && threadIdx.x < 33) {
    if (threadIdx.x == 32) {
      *counter = 0;
    } else {
      const int t   = threadIdx.x;
      const int myL = Lg[t];
      int rank = 0;
      for (int b = 0; b < BATCH; ++b) {
        const int Lb = Lg[b];
        rank += (Lb > myL) || (Lb == myL && b < t);
      }
      order[rank] = t;   // batches sorted by L descending
    }
  }
  const int total = 2 * BATCH * KLEN * (DH / 8);   // 2^21 chunks of 8
  for (int i = blockIdx.x * blockDim.x + threadIdx.x; i < total;
       i += gridDim.x * blockDim.x) {
    const int d8    = i & 15;
    const int k     = (i >> 4) & (KLEN - 1);
    const int b     = (i >> 15) & (BATCH - 1);
    const int which = i >> 20;
    const size_t off = ((size_t)b * KLEN + k) * DH + d8 * 8;
    bf16x8 val = {};
    if (k < Lg[b]) {
      const float* src = (which ? Vg : Kg) + off;
      f32x4 a = *(const f32x4*)src;
      f32x4 c = *(const f32x4*)(src + 4);
      #pragma unroll
      for (int j = 0; j < 4; ++j) { val[j] = (bf16)a[j]; val[4 + j] = (bf16)c[j]; }
    }
    *(bf16x8*)((which ? Vb : Kb) + off) = val;
  }
}

// ---- persistent dynamic-queue attention kernel ----
__global__ __launch_bounds__(256)
void fa_dyn(const float* __restrict__ Qg, const int* __restrict__ Lg,
            float* __restrict__ Og, const bf16* __restrict__ Kb,
            const bf16* __restrict__ Vb, const int* __restrict__ order,
            int* __restrict__ counter)
{
  __shared__ bf16 s_k [KVBLK * DH];    // 16 KB, swizzled
  __shared__ bf16 s_vt[DH * KVBLK];    // 16 KB, swizzled, d-major
  __shared__ int  s_item;

  const int tid  = threadIdx.x;
  const int wave = tid >> 6;
  const int lane = tid & 63;
  const int c    = lane & 31;   // q-row within wave (S^T col) / d-col (PV)
  const int hi   = lane >> 5;

  const float SC = 0.08838834764831845f * 1.4426950408889634f; // log2e/sqrt(D)

  for (;;) {
    if (tid == 0) s_item = atomicAdd(counter, 1);
    __syncthreads();
    const int item = s_item;
    if (item >= NITEMS) return;

    const int batch = order[item >> 4];
    const int qtile = item & 15;
    const int L  = Lg[batch];
    const int nt = (L + KVBLK - 1) / KVBLK;

    const size_t baseQ  = ((size_t)batch * QLEN + (size_t)qtile * QBLK) * DH;
    const size_t baseKV = (size_t)batch * KLEN * DH;

    // Q fragments: B-frag for 32x32x16: col = lane&31 (q-row), k = 8*hi + i.
    bf16x8 qf[8];
    {
      const float* qp = Qg + baseQ + (size_t)(wave * 32 + c) * DH + hi * 8;
      #pragma unroll
      for (int dc = 0; dc < 8; ++dc) {
        f32x4 a = *(const f32x4*)(qp + dc * 16);
        f32x4 b = *(const f32x4*)(qp + dc * 16 + 4);
        #pragma unroll
        for (int j = 0; j < 4; ++j) {
          qf[dc][j]     = (bf16)a[j];
          qf[dc][4 + j] = (bf16)b[j];
        }
      }
    }

    f32x16 o[4];
    #pragma unroll
    for (int db = 0; db < 4; ++db)
      #pragma unroll
      for (int j = 0; j < 16; ++j) o[db][j] = 0.f;
    float m = -__builtin_inff();
    float l = 0.f;

    // T14 prefetch registers: 8 x 16B = 32 VGPR
    bf16x8 rK[4], rV[4];
    #pragma unroll
    for (int s = 0; s < 4; ++s) {
      int id = tid + 256 * s; int key = id >> 4; int i8 = id & 15;
      rK[s] = *(const bf16x8*)(Kb + baseKV + (size_t)key * DH + i8 * 8);
    }
    #pragma unroll
    for (int s = 0; s < 2; ++s) {
      int id = tid + 256 * s; int p2 = id >> 4; int i8 = id & 15;
      rV[2 * s]     = *(const bf16x8*)(Vb + baseKV + (size_t)(2 * p2) * DH + i8 * 8);
      rV[2 * s + 1] = *(const bf16x8*)(Vb + baseKV + (size_t)(2 * p2 + 1) * DH + i8 * 8);
    }

    for (int kt = 0; kt < nt; ++kt) {
      const int k0 = kt * KVBLK;
      __syncthreads();   // prior tile/item reads done before restaging

      // ---- write prefetched regs -> LDS ----
      #pragma unroll
      for (int s = 0; s < 4; ++s) {
        int id = tid + 256 * s; int key = id >> 4; int i8 = id & 15;
        *(bf16x8*)((char*)s_k + swzK(key, i8 * 16)) = rK[s];
      }
      #pragma unroll
      for (int s = 0; s < 2; ++s) {
        int id = tid + 256 * s; int p2 = id >> 4; int i8 = id & 15;
        #pragma unroll
        for (int j = 0; j < 8; ++j) {
          bf16x2 pk = { rV[2 * s][j], rV[2 * s + 1][j] };
          *(bf16x2*)((char*)s_vt + swzV(i8 * 8 + j, p2 * 4)) = pk;
        }
      }
      __syncthreads();

      // ---- T14: issue next tile's loads; latency hides under compute ----
      if (kt + 1 < nt) {
        const int kn = k0 + KVBLK;
        #pragma unroll
        for (int s = 0; s < 4; ++s) {
          int id = tid + 256 * s; int key = id >> 4; int i8 = id & 15;
          rK[s] = *(const bf16x8*)(Kb + baseKV + (size_t)(kn + key) * DH + i8 * 8);
        }
        #pragma unroll
        for (int s = 0; s < 2; ++s) {
          int id = tid + 256 * s; int p2 = id >> 4; int i8 = id & 15;
          rV[2 * s]     = *(const bf16x8*)(Vb + baseKV + (size_t)(kn + 2 * p2) * DH + i8 * 8);
          rV[2 * s + 1] = *(const bf16x8*)(Vb + baseKV + (size_t)(kn + 2 * p2 + 1) * DH + i8 * 8);
        }
      }

      // ---- S^T = K · Q^T ----
      f32x16 st[2];
      __builtin_amdgcn_s_setprio(1);
      #pragma unroll
      for (int a = 0; a < 2; ++a) {
        #pragma unroll
        for (int j = 0; j < 16; ++j) st[a][j] = 0.f;
        int key = a * 32 + c;   // A-frag row = lane&31
        #pragma unroll
        for (int dc = 0; dc < 8; ++dc) {
          bf16x8 kf = *(const bf16x8*)((const char*)s_k + swzK(key, dc * 32 + hi * 16));
          st[a] = __builtin_amdgcn_mfma_f32_32x32x16_bf16(kf, qf[dc], st[a], 0, 0, 0);
        }
      }
      __builtin_amdgcn_s_setprio(0);

      // ---- online softmax; key(a,r,hi) = 32a + (r&3) + 8*(r>>2) + 4*hi ----
      const bool partial = (k0 + KVBLK > L);
      float pm = -__builtin_inff();
      #pragma unroll
      for (int a = 0; a < 2; ++a)
        #pragma unroll
        for (int r = 0; r < 16; ++r) {
          float s = st[a][r] * SC;
          if (partial) {
            int key = k0 + a * 32 + (r & 3) + 8 * (r >> 2) + 4 * hi;
            if (key >= L) s = -__builtin_inff();
          }
          st[a][r] = s;
          pm = fmaxf(pm, s);
        }
      pm = fmaxf(pm, __shfl_xor(pm, 32));
      const float mnew = fmaxf(m, pm);
      const float fsc  = __builtin_amdgcn_exp2f(m - mnew);  // m=-inf -> 0
      m = mnew;

      // exp in place; st[a][r] becomes P
      float rs = 0.f;
      #pragma unroll
      for (int a = 0; a < 2; ++a)
        #pragma unroll
        for (int r = 0; r < 16; ++r) {
          float p = __builtin_amdgcn_exp2f(st[a][r] - mnew);
          st[a][r] = p;
          rs += p;
        }
      rs += __shfl_xor(rs, 32);
      l = l * fsc + rs;

      // ---- rescale O ----
      float fr[16];
      #pragma unroll
      for (int j = 0; j < 16; ++j)
        fr[j] = __shfl(fsc, (j & 3) + 8 * (j >> 2) + 4 * hi, 64);
      #pragma unroll
      for (int db = 0; db < 4; ++db)
        #pragma unroll
        for (int j = 0; j < 16; ++j)
          o[db][j] *= fr[j];

      // ---- O += P · V with T12 in-register P exchange ----
      // pa[kc][i] = P[key=16kc+8hi+i] = st[kc>>1][(i&3)+8(kc&1)+4hi] of lane hi'=i>>2.
      // hi=0 lane needs partner's A-bundle; hi=1 needs partner's B-bundle.
      __builtin_amdgcn_s_setprio(1);
      #pragma unroll
      for (int kc = 0; kc < 4; ++kc) {
        const int a = kc >> 1, g = kc & 1;
        bf16x4 A, Bv;
        #pragma unroll
        for (int q = 0; q < 4; ++q) {
          A[q]  = (bf16)st[a][q + 8 * g];
          Bv[q] = (bf16)st[a][q + 8 * g + 4];
        }
        U4 snd; snd.h = hi ? A : Bv;       // send what partner needs
        U4 rcv;
        rcv.u.x = (unsigned)__shfl_xor((int)snd.u.x, 32);
        rcv.u.y = (unsigned)__shfl_xor((int)snd.u.y, 32);
        bf16x4 loh = hi ? rcv.h : A;       // i=0..3 (src hi'=0)
        bf16x4 hih = hi ? Bv    : rcv.h;   // i=4..7 (src hi'=1)
        bf16x8 pa;
        #pragma unroll
        for (int q = 0; q < 4; ++q) { pa[q] = loh[q]; pa[q + 4] = hih[q]; }
        #pragma unroll
        for (int db = 0; db < 4; ++db) {
          int d = db * 32 + c;   // B-frag: col = lane&31 (d), k = key
          bf16x8 vb = *(const bf16x8*)((const char*)s_vt + swzV(d, kc * 32 + hi * 16));
          o[db] = __builtin_amdgcn_mfma_f32_32x32x16_bf16(pa, vb, o[db], 0, 0, 0);
        }
      }
      __builtin_amdgcn_s_setprio(0);
    }

    // ---- epilogue: normalize and store (f32 out) ----
    float inv[16];
    #pragma unroll
    for (int j = 0; j < 16; ++j)
      inv[j] = 1.f / __shfl(l, (j & 3) + 8 * (j >> 2) + 4 * hi, 64);

    float* op = Og + baseQ + (size_t)(wave * 32) * DH;
    #pragma unroll
    for (int db = 0; db < 4; ++db)
      #pragma unroll
      for (int j = 0; j < 16; ++j) {
        int row = (j & 3) + 8 * (j >> 2) + 4 * hi;
        op[(size_t)row * DH + db * 32 + c] = o[db][j] * inv[j];
      }
  }
}

// ---- fallback (ws too small): R3-style synchronous static kernel ----
__global__ __launch_bounds__(256)
void fa_fwd_sync(const float* __restrict__ Qg, const float* __restrict__ Kg,
                 const float* __restrict__ Vg, const int* __restrict__ Lg,
                 float* __restrict__ Og)
{
  __shared__ bf16 s_k [KVBLK * DH];
  __shared__ bf16 s_vt[DH * KVBLK];
  __shared__ bf16 s_p [4][32 * 72];

  const int tid  = threadIdx.x;
  const int wave = tid >> 6;
  const int lane = tid & 63;
  const int c    = lane & 31;
  const int hi   = lane >> 5;

  const int bid   = blockIdx.x;
  const int batch = bid & (BATCH - 1);
  const int qtile = bid >> 5;
  const int L  = Lg[batch];
  const int nt = (L + KVBLK - 1) / KVBLK;

  const size_t baseQ  = ((size_t)batch * QLEN + (size_t)qtile * QBLK) * DH;
  const size_t baseKV = (size_t)batch * KLEN * DH;

  bf16x8 qf[8];
  {
    const float* qp = Qg + baseQ + (size_t)(wave * 32 + c) * DH + hi * 8;
    #pragma unroll
    for (int dc = 0; dc < 8; ++dc) {
      f32x4 a = *(const f32x4*)(qp + dc * 16);
      f32x4 b = *(const f32x4*)(qp + dc * 16 + 4);
      #pragma unroll
      for (int j = 0; j < 4; ++j) { qf[dc][j] = (bf16)a[j]; qf[dc][4 + j] = (bf16)b[j]; }
    }
  }

  f32x16 o[4];
  #pragma unroll
  for (int db = 0; db < 4; ++db)
    #pragma unroll
    for (int j = 0; j < 16; ++j) o[db][j] = 0.f;
  float m = -__builtin_inff();
  float l = 0.f;

  bf16* pw = &s_p[wave][0];
  const float SC = 0.08838834764831845f * 1.4426950408889634f;

  for (int kt = 0; kt < nt; ++kt) {
    const int k0 = kt * KVBLK;
    __syncthreads();
    #pragma unroll
    for (int s = 0; s < 4; ++s) {
      int id  = tid + 256 * s;
      int key = id >> 4;
      int i8  = id & 15;
      bf16x8 val = {};
      if (k0 + key < L) {
        const float* src = Kg + baseKV + (size_t)(k0 + key) * DH + i8 * 8;
        f32x4 a = *(const f32x4*)(src);
        f32x4 b = *(const f32x4*)(src + 4);
        #pragma unroll
        for (int j = 0; j < 4; ++j) { val[j] = (bf16)a[j]; val[4 + j] = (bf16)b[j]; }
      }
      *(bf16x8*)((char*)s_k + swzK(key, i8 * 16)) = val;
    }
    #pragma unroll
    for (int s = 0; s < 2; ++s) {
      int id = tid + 256 * s;
      int p2 = id >> 4;
      int i8 = id & 15;
      f32x4 v0a = {}, v0b = {}, v1a = {}, v1b = {};
      if (k0 + 2 * p2 < L) {
        const float* src = Vg + baseKV + (size_t)(k0 + 2 * p2) * DH + i8 * 8;
        v0a = *(const f32x4*)(src); v0b = *(const f32x4*)(src + 4);
      }
      if (k0 + 2 * p2 + 1 < L) {
        const float* src = Vg + baseKV + (size_t)(k0 + 2 * p2 + 1) * DH + i8 * 8;
        v1a = *(const f32x4*)(src); v1b = *(const f32x4*)(src + 4);
      }
      #pragma unroll
      for (int j = 0; j < 8; ++j) {
        int d = i8 * 8 + j;
        float f0 = (j < 4) ? v0a[j & 3] : v0b[j & 3];
        float f1 = (j < 4) ? v1a[j & 3] : v1b[j & 3];
        bf16x2 pk = { (bf16)f0, (bf16)f1 };
        *(bf16x2*)((char*)s_vt + swzV(d, p2 * 4)) = pk;
      }
    }
    __syncthreads();

    f32x16 st[2];
    #pragma unroll
    for (int a = 0; a < 2; ++a) {
      #pragma unroll
      for (int j = 0; j < 16; ++j) st[a][j] = 0.f;
      int key = a * 32 + c;
      #pragma unroll
      for (int dc = 0; dc < 8; ++dc) {
        bf16x8 kf = *(const bf16x8*)((const char*)s_k + swzK(key, dc * 32 + hi * 16));
        st[a] = __builtin_amdgcn_mfma_f32_32x32x16_bf16(kf, qf[dc], st[a], 0, 0, 0);
      }
    }

    const bool partial = (k0 + KVBLK > L);
    float pm = -__builtin_inff();
    #pragma unroll
    for (int a = 0; a < 2; ++a)
      #pragma unroll
      for (int r = 0; r < 16; ++r) {
        float s = st[a][r] * SC;
        if (partial) {
          int key = k0 + a * 32 + (r & 3) + 8 * (r >> 2) + 4 * hi;
          if (key >= L) s = -__builtin_inff();
        }
        st[a][r] = s;
        pm = fmaxf(pm, s);
      }
    pm = fmaxf(pm, __shfl_xor(pm, 32));
    const float mnew = fmaxf(m, pm);
    const float fsc  = __builtin_amdgcn_exp2f(m - mnew);
    m = mnew;

    float rs = 0.f;
    #pragma unroll
    for (int a = 0; a < 2; ++a)
      #pragma unroll
      for (int rr = 0; rr < 4; ++rr) {
        bf16x4 pk;
        #pragma unroll
        for (int j = 0; j < 4; ++j) {
          float p = __builtin_amdgcn_exp2f(st[a][rr * 4 + j] - mnew);
          rs += p;
          pk[j] = (bf16)p;
        }
        *(bf16x4*)(pw + c * 72 + a * 32 + rr * 8 + hi * 4) = pk;
      }
    rs += __shfl_xor(rs, 32);
    l = l * fsc + rs;

    float fr[16];
    #pragma unroll
    for (int j = 0; j < 16; ++j)
      fr[j] = __shfl(fsc, (j & 3) + 8 * (j >> 2) + 4 * hi, 64);
    #pragma unroll
    for (int db = 0; db < 4; ++db)
      #pragma unroll
      for (int j = 0; j < 16; ++j)
        o[db][j] *= fr[j];

    #pragma unroll
    for (int kc = 0; kc < 4; ++kc) {
      bf16x8 pa = *(const bf16x8*)(pw + c * 72 + kc * 16 + hi * 8);
      #pragma unroll
      for (int db = 0; db < 4; ++db) {
        int d = db * 32 + c;
        bf16x8 vb = *(const bf16x8*)((const char*)s_vt + swzV(d, kc * 32 + hi * 16));
        o[db] = __builtin_amdgcn_mfma_f32_32x32x16_bf16(pa, vb, o[db], 0, 0, 0);
      }
    }
  }

  float inv[16];
  #pragma unroll
  for (int j = 0; j < 16; ++j)
    inv[j] = 1.f / __shfl(l, (j & 3) + 8 * (j >> 2) + 4 * hi, 64);

  float* op = Og + baseQ + (size_t)(wave * 32) * DH;
  #pragma unroll
  for (int db = 0; db < 4; ++db)
    #pragma unroll
    for (int j = 0; j < 16; ++j) {
      int row = (j & 3) + 8 * (j >> 2) + 4 * hi;
      op[(size_t)row * DH + db * 32 + c] = o[db][j] * inv[j];
    }
}

extern "C" void kernel_launch(void* const* d_in, const int* in_sizes, int n_in,
                              void* d_out, int out_size, void* d_ws, size_t ws_size,
                              hipStream_t stream) {
  const float* q = (const float*)d_in[0];
  const float* k = (const float*)d_in[1];
  const float* v = (const float*)d_in[2];
  const int* lens = (const int*)d_in[3];
  float* out = (float*)d_out;

  const size_t elems = (size_t)BATCH * KLEN * DH;
  const size_t need  = 2 * elems * sizeof(bf16) + 256;   // Kb+Vb+plan
  if (ws_size >= need) {
    bf16* Kb = (bf16*)d_ws;
    bf16* Vb = Kb + elems;
    int* counter = (int*)((char*)d_ws + 2 * elems * sizeof(bf16));
    int* order   = counter + 1;
    hipLaunchKernelGGL(conv_kv, dim3(2048), dim3(256), 0, stream,
                       k, v, lens, Kb, Vb, order, counter);
    hipLaunchKernelGGL(fa_dyn, dim3(768), dim3(256), 0, stream,
                       q, lens, out, Kb, Vb, order, counter);
  } else {
    hipLaunchKernelGGL(fa_fwd_sync, dim3(BATCH * (QLEN / QBLK)), dim3(256),
                       0, stream, q, k, v, lens, out);
  }
}

// Round 6
// 112.441 us; speedup vs baseline: 2.4360x; 1.0799x over previous
//
#include <hip/hip_runtime.h>

// Masked dot-product attention. INPUTS float32, OUTPUT float32.
// B=32, Q=K=2048, D=128. Flash-style online softmax,
// swapped-QK^T 32x32x16 bf16 MFMA structure.
// R6: double-buffered LDS with ONE barrier per KV tile (writes overlapped
// with softmax/PV), V staging via ds_write_b64, T13 defer-max rescale,
// scale*log2e folded into Q fragments. Keeps bf16 pre-pass, dynamic LPT
// queue, T14 register prefetch, T12 in-register P exchange, T5 setprio.

using bf16   = __bf16;
using bf16x2 = __attribute__((ext_vector_type(2)))  __bf16;
using bf16x4 = __attribute__((ext_vector_type(4)))  __bf16;
using bf16x8 = __attribute__((ext_vector_type(8)))  __bf16;
using f32x4  = __attribute__((ext_vector_type(4)))  float;
using f32x16 = __attribute__((ext_vector_type(16))) float;

constexpr int BATCH  = 32;
constexpr int QLEN   = 2048;
constexpr int KLEN   = 2048;
constexpr int DH     = 128;
constexpr int QBLK   = 128;   // q-rows per item (4 waves x 32)
constexpr int KVBLK  = 64;    // kv tile
constexpr int NITEMS = BATCH * (QLEN / QBLK);   // 512

union U4 { bf16x4 h; uint2 u; };

// K tile: [64 keys][128 d] bf16, row stride 256B, XOR swizzle by key.
__device__ __forceinline__ int swzK(int key, int byteoff) {
  return (key * 256 + byteoff) ^ ((key & 7) << 4);
}
// V^T tile: [128 d][64 keys] bf16, row stride 128B.
__device__ __forceinline__ int swzV(int d, int byteoff) {
  return (d * 128 + byteoff) ^ (((d ^ (d >> 3)) & 7) << 4);
}

// ---- pre-pass: K,V f32 -> bf16 (zero past valid_len) + LPT plan ----
__global__ __launch_bounds__(256)
void conv_kv(const float* __restrict__ Kg, const float* __restrict__ Vg,
             const int* __restrict__ Lg, bf16* __restrict__ Kb,
             bf16* __restrict__ Vb, int* __restrict__ order,
             int* __restrict__ counter)
{
  if (blockIdx.x == 0 && threadIdx.x < 33) {
    if (threadIdx.x == 32) {
      *counter = 0;
    } else {
      const int t   = threadIdx.x;
      const int myL = Lg[t];
      int rank = 0;
      for (int b = 0; b < BATCH; ++b) {
        const int Lb = Lg[b];
        rank += (Lb > myL) || (Lb == myL && b < t);
      }
      order[rank] = t;   // batches sorted by L descending
    }
  }
  const int total = 2 * BATCH * KLEN * (DH / 8);   // 2^21 chunks of 8
  for (int i = blockIdx.x * blockDim.x + threadIdx.x; i < total;
       i += gridDim.x * blockDim.x) {
    const int d8    = i & 15;
    const int k     = (i >> 4) & (KLEN - 1);
    const int b     = (i >> 15) & (BATCH - 1);
    const int which = i >> 20;
    const size_t off = ((size_t)b * KLEN + k) * DH + d8 * 8;
    bf16x8 val = {};
    if (k < Lg[b]) {
      const float* src = (which ? Vg : Kg) + off;
      f32x4 a = *(const f32x4*)src;
      f32x4 c = *(const f32x4*)(src + 4);
      #pragma unroll
      for (int j = 0; j < 4; ++j) { val[j] = (bf16)a[j]; val[4 + j] = (bf16)c[j]; }
    }
    *(bf16x8*)((which ? Vb : Kb) + off) = val;
  }
}

// ---- persistent dynamic-queue attention kernel ----
__global__ __launch_bounds__(256)
void fa_dyn(const float* __restrict__ Qg, const int* __restrict__ Lg,
            float* __restrict__ Og, const bf16* __restrict__ Kb,
            const bf16* __restrict__ Vb, const int* __restrict__ order,
            int* __restrict__ counter)
{
  __shared__ bf16 s_k [2][KVBLK * DH];    // 2 x 16 KB, swizzled
  __shared__ bf16 s_vt[2][DH * KVBLK];    // 2 x 16 KB, swizzled, d-major
  __shared__ int  s_item;

  const int tid  = threadIdx.x;
  const int wave = tid >> 6;
  const int lane = tid & 63;
  const int c    = lane & 31;   // q-row within wave (S^T col) / d-col (PV)
  const int hi   = lane >> 5;
  const int vp4  = tid >> 4;    // V staging: key-quad 0..15
  const int vi8  = tid & 15;    // V staging: d-chunk of 8

  const float SC = 0.08838834764831845f * 1.4426950408889634f; // log2e/sqrt(D)

  for (;;) {
    if (tid == 0) s_item = atomicAdd(counter, 1);
    __syncthreads();   // also guards LDS reuse across items
    const int item = s_item;
    if (item >= NITEMS) return;

    const int batch = order[item >> 4];
    const int qtile = item & 15;
    const int L  = Lg[batch];
    const int nt = (L + KVBLK - 1) / KVBLK;

    const size_t baseQ  = ((size_t)batch * QLEN + (size_t)qtile * QBLK) * DH;
    const size_t baseKV = (size_t)batch * KLEN * DH;

    // Q fragments pre-scaled by SC (kills 32 v_mul per tile).
    // B-frag for 32x32x16: col = lane&31 (q-row), k = 8*hi + i (d).
    bf16x8 qf[8];
    {
      const float* qp = Qg + baseQ + (size_t)(wave * 32 + c) * DH + hi * 8;
      #pragma unroll
      for (int dc = 0; dc < 8; ++dc) {
        f32x4 a = *(const f32x4*)(qp + dc * 16);
        f32x4 b = *(const f32x4*)(qp + dc * 16 + 4);
        #pragma unroll
        for (int j = 0; j < 4; ++j) {
          qf[dc][j]     = (bf16)(a[j] * SC);
          qf[dc][4 + j] = (bf16)(b[j] * SC);
        }
      }
    }

    f32x16 o[4];
    #pragma unroll
    for (int db = 0; db < 4; ++db)
      #pragma unroll
      for (int j = 0; j < 16; ++j) o[db][j] = 0.f;
    float m = -__builtin_inff();
    float l = 0.f;

    // T14 prefetch registers: 8 x 16B = 32 VGPR
    bf16x8 rK[4], rV[4];
    auto loadKV = [&](int k0) {
      #pragma unroll
      for (int s = 0; s < 4; ++s) {
        int id = tid + 256 * s; int key = id >> 4; int i8 = id & 15;
        rK[s] = *(const bf16x8*)(Kb + baseKV + (size_t)(k0 + key) * DH + i8 * 8);
      }
      #pragma unroll
      for (int s = 0; s < 4; ++s)
        rV[s] = *(const bf16x8*)(Vb + baseKV + (size_t)(k0 + 4 * vp4 + s) * DH + vi8 * 8);
    };
    auto writeKV = [&](int buf) {
      #pragma unroll
      for (int s = 0; s < 4; ++s) {
        int id = tid + 256 * s; int key = id >> 4; int i8 = id & 15;
        *(bf16x8*)((char*)s_k[buf] + swzK(key, i8 * 16)) = rK[s];
      }
      #pragma unroll
      for (int j = 0; j < 8; ++j) {   // 8 x ds_write_b64 (key-quad per write)
        bf16x4 w = { rV[0][j], rV[1][j], rV[2][j], rV[3][j] };
        *(bf16x4*)((char*)s_vt[buf] + swzV(vi8 * 8 + j, vp4 * 8)) = w;
      }
    };

    loadKV(0);
    writeKV(0);

    for (int kt = 0; kt < nt; ++kt) {
      const int cur = kt & 1;
      const int k0  = kt * KVBLK;
      __syncthreads();   // buf[cur] writes visible; buf[cur^1] free for restage

      const bool more = (kt + 1 < nt);
      if (more) loadKV(k0 + KVBLK);   // issue early; hides under compute

      // ---- S^T = K · Q^T (log2-scaled since Q pre-scaled) ----
      f32x16 st[2];
      __builtin_amdgcn_s_setprio(1);
      #pragma unroll
      for (int a = 0; a < 2; ++a) {
        #pragma unroll
        for (int j = 0; j < 16; ++j) st[a][j] = 0.f;
        int key = a * 32 + c;   // A-frag row = lane&31
        #pragma unroll
        for (int dc = 0; dc < 8; ++dc) {
          bf16x8 kf = *(const bf16x8*)((const char*)s_k[cur] + swzK(key, dc * 32 + hi * 16));
          st[a] = __builtin_amdgcn_mfma_f32_32x32x16_bf16(kf, qf[dc], st[a], 0, 0, 0);
        }
      }
      __builtin_amdgcn_s_setprio(0);

      // ---- online softmax; key(a,r,hi) = 32a + (r&3) + 8*(r>>2) + 4*hi ----
      const bool partial = (k0 + KVBLK > L);
      float pm = -__builtin_inff();
      #pragma unroll
      for (int a = 0; a < 2; ++a)
        #pragma unroll
        for (int r = 0; r < 16; ++r) {
          float s = st[a][r];
          if (partial) {
            int key = k0 + a * 32 + (r & 3) + 8 * (r >> 2) + 4 * hi;
            if (key >= L) s = -__builtin_inff();
          }
          st[a][r] = s;
          pm = fmaxf(pm, s);
        }
      const float pmw = fmaxf(pm, __shfl_xor(pm, 32));

      // T13 defer-max: skip rescale while tile max stays within 8 of m
      const bool resc = !__all(pmw <= m + 8.f);
      float fsc = 1.f;
      if (resc) {
        const float mnew = fmaxf(m, pmw);
        fsc = __builtin_amdgcn_exp2f(m - mnew);   // m=-inf -> 0
        m = mnew;
      }

      float rs = 0.f;
      #pragma unroll
      for (int a = 0; a < 2; ++a)
        #pragma unroll
        for (int r = 0; r < 16; ++r) {
          float p = __builtin_amdgcn_exp2f(st[a][r] - m);
          st[a][r] = p;
          rs += p;
        }
      rs += __shfl_xor(rs, 32);
      l = l * fsc + rs;

      // ---- restage next tile into the other buffer (hidden under VALU) ----
      if (more) writeKV(cur ^ 1);

      if (resc) {
        float fr[16];
        #pragma unroll
        for (int j = 0; j < 16; ++j)
          fr[j] = __shfl(fsc, (j & 3) + 8 * (j >> 2) + 4 * hi, 64);
        #pragma unroll
        for (int db = 0; db < 4; ++db)
          #pragma unroll
          for (int j = 0; j < 16; ++j)
            o[db][j] *= fr[j];
      }

      // ---- O += P · V with T12 in-register P exchange ----
      // pa[kc][i] = P[key=16kc+8hi+i] = st[kc>>1][(i&3)+8(kc&1)+4hi] @ lane hi'=i>>2
      __builtin_amdgcn_s_setprio(1);
      #pragma unroll
      for (int kc = 0; kc < 4; ++kc) {
        const int a = kc >> 1, g = kc & 1;
        bf16x4 A, Bv;
        #pragma unroll
        for (int q = 0; q < 4; ++q) {
          A[q]  = (bf16)st[a][q + 8 * g];
          Bv[q] = (bf16)st[a][q + 8 * g + 4];
        }
        U4 snd; snd.h = hi ? A : Bv;       // send what partner needs
        U4 rcv;
        rcv.u.x = (unsigned)__shfl_xor((int)snd.u.x, 32);
        rcv.u.y = (unsigned)__shfl_xor((int)snd.u.y, 32);
        bf16x4 loh = hi ? rcv.h : A;       // i=0..3 (src hi'=0)
        bf16x4 hih = hi ? Bv    : rcv.h;   // i=4..7 (src hi'=1)
        bf16x8 pa;
        #pragma unroll
        for (int q = 0; q < 4; ++q) { pa[q] = loh[q]; pa[q + 4] = hih[q]; }
        #pragma unroll
        for (int db = 0; db < 4; ++db) {
          int d = db * 32 + c;   // B-frag: col = lane&31 (d), k = key
          bf16x8 vb = *(const bf16x8*)((const char*)s_vt[cur] + swzV(d, kc * 32 + hi * 16));
          o[db] = __builtin_amdgcn_mfma_f32_32x32x16_bf16(pa, vb, o[db], 0, 0, 0);
        }
      }
      __builtin_amdgcn_s_setprio(0);
    }

    // ---- epilogue: normalize and store (f32 out) ----
    float inv[16];
    #pragma unroll
    for (int j = 0; j < 16; ++j)
      inv[j] = 1.f / __shfl(l, (j & 3) + 8 * (j >> 2) + 4 * hi, 64);

    float* op = Og + baseQ + (size_t)(wave * 32) * DH;
    #pragma unroll
    for (int db = 0; db < 4; ++db)
      #pragma unroll
      for (int j = 0; j < 16; ++j) {
        int row = (j & 3) + 8 * (j >> 2) + 4 * hi;
        op[(size_t)row * DH + db * 32 + c] = o[db][j] * inv[j];
      }
  }
}

// ---- fallback (ws too small): R3-style synchronous static kernel ----
__global__ __launch_bounds__(256)
void fa_fwd_sync(const float* __restrict__ Qg, const float* __restrict__ Kg,
                 const float* __restrict__ Vg, const int* __restrict__ Lg,
                 float* __restrict__ Og)
{
  __shared__ bf16 s_k [KVBLK * DH];
  __shared__ bf16 s_vt[DH * KVBLK];
  __shared__ bf16 s_p [4][32 * 72];

  const int tid  = threadIdx.x;
  const int wave = tid >> 6;
  const int lane = tid & 63;
  const int c    = lane & 31;
  const int hi   = lane >> 5;

  const int bid   = blockIdx.x;
  const int batch = bid & (BATCH - 1);
  const int qtile = bid >> 5;
  const int L  = Lg[batch];
  const int nt = (L + KVBLK - 1) / KVBLK;

  const size_t baseQ  = ((size_t)batch * QLEN + (size_t)qtile * QBLK) * DH;
  const size_t baseKV = (size_t)batch * KLEN * DH;

  bf16x8 qf[8];
  {
    const float* qp = Qg + baseQ + (size_t)(wave * 32 + c) * DH + hi * 8;
    #pragma unroll
    for (int dc = 0; dc < 8; ++dc) {
      f32x4 a = *(const f32x4*)(qp + dc * 16);
      f32x4 b = *(const f32x4*)(qp + dc * 16 + 4);
      #pragma unroll
      for (int j = 0; j < 4; ++j) { qf[dc][j] = (bf16)a[j]; qf[dc][4 + j] = (bf16)b[j]; }
    }
  }

  f32x16 o[4];
  #pragma unroll
  for (int db = 0; db < 4; ++db)
    #pragma unroll
    for (int j = 0; j < 16; ++j) o[db][j] = 0.f;
  float m = -__builtin_inff();
  float l = 0.f;

  bf16* pw = &s_p[wave][0];
  const float SC = 0.08838834764831845f * 1.4426950408889634f;

  for (int kt = 0; kt < nt; ++kt) {
    const int k0 = kt * KVBLK;
    __syncthreads();
    #pragma unroll
    for (int s = 0; s < 4; ++s) {
      int id  = tid + 256 * s;
      int key = id >> 4;
      int i8  = id & 15;
      bf16x8 val = {};
      if (k0 + key < L) {
        const float* src = Kg + baseKV + (size_t)(k0 + key) * DH + i8 * 8;
        f32x4 a = *(const f32x4*)(src);
        f32x4 b = *(const f32x4*)(src + 4);
        #pragma unroll
        for (int j = 0; j < 4; ++j) { val[j] = (bf16)a[j]; val[4 + j] = (bf16)b[j]; }
      }
      *(bf16x8*)((char*)s_k + swzK(key, i8 * 16)) = val;
    }
    #pragma unroll
    for (int s = 0; s < 2; ++s) {
      int id = tid + 256 * s;
      int p2 = id >> 4;
      int i8 = id & 15;
      f32x4 v0a = {}, v0b = {}, v1a = {}, v1b = {};
      if (k0 + 2 * p2 < L) {
        const float* src = Vg + baseKV + (size_t)(k0 + 2 * p2) * DH + i8 * 8;
        v0a = *(const f32x4*)(src); v0b = *(const f32x4*)(src + 4);
      }
      if (k0 + 2 * p2 + 1 < L) {
        const float* src = Vg + baseKV + (size_t)(k0 + 2 * p2 + 1) * DH + i8 * 8;
        v1a = *(const f32x4*)(src); v1b = *(const f32x4*)(src + 4);
      }
      #pragma unroll
      for (int j = 0; j < 8; ++j) {
        int d = i8 * 8 + j;
        float f0 = (j < 4) ? v0a[j & 3] : v0b[j & 3];
        float f1 = (j < 4) ? v1a[j & 3] : v1b[j & 3];
        bf16x2 pk = { (bf16)f0, (bf16)f1 };
        *(bf16x2*)((char*)s_vt + swzV(d, p2 * 4)) = pk;
      }
    }
    __syncthreads();

    f32x16 st[2];
    #pragma unroll
    for (int a = 0; a < 2; ++a) {
      #pragma unroll
      for (int j = 0; j < 16; ++j) st[a][j] = 0.f;
      int key = a * 32 + c;
      #pragma unroll
      for (int dc = 0; dc < 8; ++dc) {
        bf16x8 kf = *(const bf16x8*)((const char*)s_k + swzK(key, dc * 32 + hi * 16));
        st[a] = __builtin_amdgcn_mfma_f32_32x32x16_bf16(kf, qf[dc], st[a], 0, 0, 0);
      }
    }

    const bool partial = (k0 + KVBLK > L);
    float pm = -__builtin_inff();
    #pragma unroll
    for (int a = 0; a < 2; ++a)
      #pragma unroll
      for (int r = 0; r < 16; ++r) {
        float s = st[a][r] * SC;
        if (partial) {
          int key = k0 + a * 32 + (r & 3) + 8 * (r >> 2) + 4 * hi;
          if (key >= L) s = -__builtin_inff();
        }
        st[a][r] = s;
        pm = fmaxf(pm, s);
      }
    pm = fmaxf(pm, __shfl_xor(pm, 32));
    const float mnew = fmaxf(m, pm);
    const float fsc  = __builtin_amdgcn_exp2f(m - mnew);
    m = mnew;

    float rs = 0.f;
    #pragma unroll
    for (int a = 0; a < 2; ++a)
      #pragma unroll
      for (int rr = 0; rr < 4; ++rr) {
        bf16x4 pk;
        #pragma unroll
        for (int j = 0; j < 4; ++j) {
          float p = __builtin_amdgcn_exp2f(st[a][rr * 4 + j] - mnew);
          rs += p;
          pk[j] = (bf16)p;
        }
        *(bf16x4*)(pw + c * 72 + a * 32 + rr * 8 + hi * 4) = pk;
      }
    rs += __shfl_xor(rs, 32);
    l = l * fsc + rs;

    float fr[16];
    #pragma unroll
    for (int j = 0; j < 16; ++j)
      fr[j] = __shfl(fsc, (j & 3) + 8 * (j >> 2) + 4 * hi, 64);
    #pragma unroll
    for (int db = 0; db < 4; ++db)
      #pragma unroll
      for (int j = 0; j < 16; ++j)
        o[db][j] *= fr[j];

    #pragma unroll
    for (int kc = 0; kc < 4; ++kc) {
      bf16x8 pa = *(const bf16x8*)(pw + c * 72 + kc * 16 + hi * 8);
      #pragma unroll
      for (int db = 0; db < 4; ++db) {
        int d = db * 32 + c;
        bf16x8 vb = *(const bf16x8*)((const char*)s_vt + swzV(d, kc * 32 + hi * 16));
        o[db] = __builtin_amdgcn_mfma_f32_32x32x16_bf16(pa, vb, o[db], 0, 0, 0);
      }
    }
  }

  float inv[16];
  #pragma unroll
  for (int j = 0; j < 16; ++j)
    inv[j] = 1.f / __shfl(l, (j & 3) + 8 * (j >> 2) + 4 * hi, 64);

  float* op = Og + baseQ + (size_t)(wave * 32) * DH;
  #pragma unroll
  for (int db = 0; db < 4; ++db)
    #pragma unroll
    for (int j = 0; j < 16; ++j) {
      int row = (j & 3) + 8 * (j >> 2) + 4 * hi;
      op[(size_t)row * DH + db * 32 + c] = o[db][j] * inv[j];
    }
}

extern "C" void kernel_launch(void* const* d_in, const int* in_sizes, int n_in,
                              void* d_out, int out_size, void* d_ws, size_t ws_size,
                              hipStream_t stream) {
  const float* q = (const float*)d_in[0];
  const float* k = (const float*)d_in[1];
  const float* v = (const float*)d_in[2];
  const int* lens = (const int*)d_in[3];
  float* out = (float*)d_out;

  const size_t elems = (size_t)BATCH * KLEN * DH;
  const size_t need  = 2 * elems * sizeof(bf16) + 256;   // Kb+Vb+plan
  if (ws_size >= need) {
    bf16* Kb = (bf16*)d_ws;
    bf16* Vb = Kb + elems;
    int* counter = (int*)((char*)d_ws + 2 * elems * sizeof(bf16));
    int* order   = counter + 1;
    hipLaunchKernelGGL(conv_kv, dim3(2048), dim3(256), 0, stream,
                       k, v, lens, Kb, Vb, order, counter);
    hipLaunchKernelGGL(fa_dyn, dim3(768), dim3(256), 0, stream,
                       q, lens, out, Kb, Vb, order, counter);
  } else {
    hipLaunchKernelGGL(fa_fwd_sync, dim3(BATCH * (QLEN / QBLK)), dim3(256),
                       0, stream, q, k, v, lens, out);
  }
}